// Round 3
// baseline (87.216 us; speedup 1.0000x reference)
//
#include <hip/hip_runtime.h>

// LocallyConnected2d: x(16,3,128,128) f32, W(61,61,64,3,8,8) f32, bias(64,61,61) f32
// out(16,1,488,488) f32; stride 2, kernel 8, no pad; pixel-shuffle r=8 epilogue.
//
// R2: persistent double-buffered stream. 256 blocks (1/CU, 120 KB LDS), each
// processes ~14.5 hw tiles. Per tile: issue next tile's W+x via
// global_load_lds (24 instr/wave), counted s_waitcnt vmcnt(24) + raw
// s_barrier (prefetch stays in flight across the barrier), compute (R1's
// validated 4oc x 4b x K/4 mapping + XOR-swizzled W), second barrier releases
// the buffer, shfl-combine + store. Bias loaded BEFORE the prefetch batch so
// FIFO vmcnt retirement never waits on the prefetch.

namespace {
constexpr int NHW   = 61 * 61;       // 3721
constexpr int Kd    = 192;           // 3*8*8
constexpr int OC    = 64;
constexpr int BATCH = 16;
constexpr int XB    = 3 * 128 * 128;
constexpr int XCC   = 128 * 128;
constexpr int OSTR  = 488 * 488;
constexpr int GRID  = 256;

__device__ __forceinline__ int swz(int oc) { return (oc ^ (oc >> 3)) & 7; }
}

__global__ __launch_bounds__(256, 1) void lc2d_kernel(
    const float* __restrict__ xg,   // [16][3][128][128]
    const float* __restrict__ wg,   // [61][61][64][3][8][8]
    const float* __restrict__ bg,   // [64][61][61]
    float* __restrict__ og)         // [16][488][488]
{
    __shared__ float4 wl[2][OC * 48];                  // 96 KB, swizzled rows
    __shared__ __align__(16) float xl[2][BATCH * Kd];  // 24 KB, linear [b][k]

    const int bid  = blockIdx.x;
    const int t    = threadIdx.x;
    const int lane = t & 63;
    const int wv   = t >> 6;
    const int nt   = 14 + (bid < (NHW - 14 * GRID));   // 137 blocks get 15

    const int q  = lane & 15;   // oc quad
    const int kh = lane >> 4;   // K/4 slice

    // issue one tile's staging: 12x W(16B/lane, 1KB) + 12x x(4B/lane, 256B) per wave
    auto issue_tile = [&](int hw, int p) {
        const float* wbase = wg + (size_t)hw * (OC * Kd);
        #pragma unroll
        for (int ci = 0; ci < 12; ++ci) {
            const int s   = wv * 768 + ci * 64 + lane;   // float4 slot
            const int ocs = s / 48;
            const int t4  = s - ocs * 48;
            const int k4  = t4 ^ swz(ocs);               // pre-swizzled source
            __builtin_amdgcn_global_load_lds(
                (const __attribute__((address_space(1))) void*)(wbase + (ocs * 48 + k4) * 4),
                (__attribute__((address_space(3))) void*)&wl[p][wv * 768 + ci * 64],
                16, 0, 0);
        }
        const int hh = hw / 61;
        const int ww = hw - hh * 61;
        const float* xb = xg + (hh * 2) * 128 + (ww * 2);
        #pragma unroll
        for (int ci = 0; ci < 12; ++ci) {
            const int g  = (wv * 12 + ci) * 64 + lane;   // float slot 0..3071
            const int b  = g / 192;
            const int r  = g - b * 192;
            const int c  = r >> 6;
            const int r2 = r & 63;
            const int ii = r2 >> 3;
            const int cl = r2 & 7;
            __builtin_amdgcn_global_load_lds(
                (const __attribute__((address_space(1))) void*)(xb + b * XB + c * XCC + ii * 128 + cl),
                (__attribute__((address_space(3))) void*)&xl[p][(wv * 12 + ci) * 64],
                4, 0, 0);
        }
    };

    issue_tile(bid, 0);   // prologue: tile 0 -> buf 0

    int p = 0;
    for (int i = 0; i < nt; ++i) {
        const int hw = bid + i * GRID;
        const int h  = hw / 61;
        const int w  = hw - h * 61;

        // bias BEFORE prefetch issue (FIFO: consuming it never drains prefetch)
        float bz[4];
        #pragma unroll
        for (int j = 0; j < 4; ++j) bz[j] = bg[(q * 4 + j) * NHW + hw];
        asm volatile("" ::: "memory");

        if (i + 1 < nt) {
            issue_tile(bid + (i + 1) * GRID, p ^ 1);
            asm volatile("s_waitcnt vmcnt(24)" ::: "memory");  // tile i landed; next 24 in flight
        } else {
            asm volatile("s_waitcnt vmcnt(0)" ::: "memory");
        }
        __builtin_amdgcn_s_barrier();
        __builtin_amdgcn_sched_barrier(0);

        const float4* wlp = &wl[p][0];
        const float*  xlp = &xl[p][0];
        const int kbase = kh * 12;   // float4 units

        float acc[4][4];
        #pragma unroll
        for (int j = 0; j < 4; ++j)
            #pragma unroll
            for (int bb = 0; bb < 4; ++bb) acc[j][bb] = 0.f;

        #pragma unroll
        for (int kk = 0; kk < 12; ++kk) {
            float4 wv4[4];
            #pragma unroll
            for (int j = 0; j < 4; ++j) {
                const int oc = q * 4 + j;
                wv4[j] = wlp[oc * 48 + ((kbase + kk) ^ swz(oc))];
            }
            #pragma unroll
            for (int bb = 0; bb < 4; ++bb) {
                const float4 xv = *reinterpret_cast<const float4*>(
                    &xlp[(wv * 4 + bb) * Kd + (kbase + kk) * 4]);
                #pragma unroll
                for (int j = 0; j < 4; ++j) {
                    acc[j][bb] = fmaf(wv4[j].x, xv.x, acc[j][bb]);
                    acc[j][bb] = fmaf(wv4[j].y, xv.y, acc[j][bb]);
                    acc[j][bb] = fmaf(wv4[j].z, xv.z, acc[j][bb]);
                    acc[j][bb] = fmaf(wv4[j].w, xv.w, acc[j][bb]);
                }
            }
        }

        __builtin_amdgcn_sched_barrier(0);
        asm volatile("s_waitcnt lgkmcnt(0)" ::: "memory");
        __builtin_amdgcn_s_barrier();      // all waves done reading buf[p]
        __builtin_amdgcn_sched_barrier(0);

        // K-combine (lanes xor 16/32) + bias + pixel-shuffle store
        #pragma unroll
        for (int j = 0; j < 4; ++j)
            #pragma unroll
            for (int bb = 0; bb < 4; ++bb) {
                acc[j][bb] += __shfl_xor(acc[j][bb], 16);
                acc[j][bb] += __shfl_xor(acc[j][bb], 32);
            }

        const int b    = wv * 4 + kh;
        const int orow = h * 8 + (q >> 1);
        const int ocol = w * 8 + (q & 1) * 4;
        float4 ov;
        ov.x = acc[0][kh] + bz[0];
        ov.y = acc[1][kh] + bz[1];
        ov.z = acc[2][kh] + bz[2];
        ov.w = acc[3][kh] + bz[3];
        *reinterpret_cast<float4*>(og + (size_t)b * OSTR + orow * 488 + ocol) = ov;

        p ^= 1;
    }
}

extern "C" void kernel_launch(void* const* d_in, const int* in_sizes, int n_in,
                              void* d_out, int out_size, void* d_ws, size_t ws_size,
                              hipStream_t stream) {
    const float* x    = (const float*)d_in[0];
    const float* W    = (const float*)d_in[1];
    const float* bias = (const float*)d_in[2];
    float* out        = (float*)d_out;
    lc2d_kernel<<<dim3(GRID), dim3(256), 0, stream>>>(x, W, bias, out);
}